// Round 6
// baseline (196.924 us; speedup 1.0000x reference)
//
#include <hip/hip_runtime.h>
#include <math.h>

#define NTOK 8192
#define DD   2048
#define EE   64
#define TSTRIP 16            // tokens per block
#define NKW 8                // waves per block (K sub-slices)
#define KSPL 2               // K-split across blocks
#define DW 128               // d-values per wave
#define NCH (DW/32)          // 4 chunks per wave
#define PROB_N (NTOK*2)
// F (swizzled W) layout: [s:3][ck:128][nt:4][lane:64][j:8] bf16, 1.5 MB
#define F_SSTRIDE (128*4*64*8)

typedef __bf16 bf16x8 __attribute__((ext_vector_type(8)));
typedef float  f32x4  __attribute__((ext_vector_type(4)));
typedef unsigned int u32x4 __attribute__((ext_vector_type(4)));

// exact truncation 3-split (scalar)
__device__ __forceinline__ void tsplit3(float x, unsigned short& h1,
                                        unsigned short& h2, unsigned short& h3) {
    const unsigned u = __builtin_bit_cast(unsigned, x);
    h1 = (unsigned short)(u >> 16);
    const float f1 = __builtin_bit_cast(float, u & 0xFFFF0000u);
    const float r1 = x - f1;
    const unsigned v = __builtin_bit_cast(unsigned, r1);
    h2 = (unsigned short)(v >> 16);
    const float f2 = __builtin_bit_cast(float, v & 0xFFFF0000u);
    const float r2 = r1 - f2;
    h3 = (unsigned short)(__builtin_bit_cast(unsigned, r2) >> 16);
}

// fast branchless atan2 (Cephes reduction + deg-7 odd minimax), ~3e-7 abs
__device__ __forceinline__ float fast_atan2f(float y, float x) {
    const float ax = __builtin_fabsf(x), ay = __builtin_fabsf(y);
    const float hi = fmaxf(ax, ay), lo = fminf(ax, ay);
    const bool  big = lo > 0.4142135679721832f * hi;       // tan(pi/8)
    const float num = big ? (lo - hi) : lo;
    const float den = big ? (lo + hi) : hi;
    float rc = __builtin_amdgcn_rcpf(den);
    rc = rc * fmaf(-den, rc, 2.0f);                        // 1 NR step
    const float z  = num * rc;
    const float z2 = z * z;
    float p = fmaf(z2, 8.05374449538e-2f, -1.38776856032e-1f);
    p = fmaf(z2, p, 1.99777106478e-1f);
    p = fmaf(z2, p, -3.33329491539e-1f);
    float r = fmaf(z * z2, p, z);
    r = r + (big ? 0.78539816339744830962f : 0.0f);
    r = (ay > ax) ? (1.57079632679489661923f - r) : r;
    r = (x < 0.0f) ? (3.14159265358979323846f - r) : r;
    return copysignf(r, y);
}

// pack high-16s of two fp32 into one dword
__device__ __forceinline__ unsigned packhi(float a, float b) {
    return __builtin_amdgcn_perm(__builtin_bit_cast(unsigned, b),
                                 __builtin_bit_cast(unsigned, a), 0x07060302u);
}

// Build 3 bf16x8 split planes from 8 fp32 values (truncation split, exact)
__device__ __forceinline__ void split_planes(const float* v, bf16x8& o1,
                                             bf16x8& o2, bf16x8& o3) {
    u32x4 P1, P2, P3;
    #pragma unroll
    for (int p = 0; p < 4; ++p) {
        const float a = v[2 * p], b = v[2 * p + 1];
        const float f1a = __builtin_bit_cast(float, __builtin_bit_cast(unsigned, a) & 0xFFFF0000u);
        const float f1b = __builtin_bit_cast(float, __builtin_bit_cast(unsigned, b) & 0xFFFF0000u);
        const float r1a = a - f1a, r1b = b - f1b;
        const float f2a = __builtin_bit_cast(float, __builtin_bit_cast(unsigned, r1a) & 0xFFFF0000u);
        const float f2b = __builtin_bit_cast(float, __builtin_bit_cast(unsigned, r1b) & 0xFFFF0000u);
        const float r2a = r1a - f2a, r2b = r1b - f2b;
        P1[p] = packhi(a, b);
        P2[p] = packhi(r1a, r1b);
        P3[p] = packhi(r2a, r2b);
    }
    o1 = __builtin_bit_cast(bf16x8, P1);
    o2 = __builtin_bit_cast(bf16x8, P2);
    o3 = __builtin_bit_cast(bf16x8, P3);
}

// Kernel 0: split + swizzle W -> F fragment order; zero the score buffer.
__global__ __launch_bounds__(256) void wsplit(const float* __restrict__ W,
                                              unsigned short* __restrict__ F,
                                              float* __restrict__ score) {
    const int g  = blockIdx.x * 256 + threadIdx.x;   // 32768 threads
    const int e  = g & 63;
    const int q  = g >> 6;
    const int d0 = q * 4;
    const int nt = e >> 4;
    const int k  = d0 & 31;
    const int lane = (k >> 3) * 16 + (e & 15);
    const int j0 = k & 7;
    const int ck = 2 * (d0 >> 5);

    unsigned short ah[3][4], ph[3][4];
    #pragma unroll
    for (int i = 0; i < 4; ++i) {
        tsplit3(W[(size_t)(d0 + i) * EE + e],      ah[0][i], ah[1][i], ah[2][i]);
        tsplit3(W[(size_t)(DD + d0 + i) * EE + e], ph[0][i], ph[1][i], ph[2][i]);
    }
    #pragma unroll
    for (int s = 0; s < 3; ++s) {
        ushort4 va = make_ushort4(ah[s][0], ah[s][1], ah[s][2], ah[s][3]);
        ushort4 vp = make_ushort4(ph[s][0], ph[s][1], ph[s][2], ph[s][3]);
        *(ushort4*)&F[(size_t)(((s * 128 + ck)     * 4 + nt) * 64 + lane) * 8 + j0] = va;
        *(ushort4*)&F[(size_t)(((s * 128 + ck + 1) * 4 + nt) * 64 + lane) * 8 + j0] = vp;
    }
    // zero 2 MB score: 32768 threads x 4 float4
    float4* sz = (float4*)score;
    #pragma unroll
    for (int r = 0; r < 4; ++r)
        sz[(size_t)g * 4 + r] = make_float4(0.f, 0.f, 0.f, 0.f);
}

// Kernel 1: MFMA gemm at 8 waves/SIMD. Wave = 16 tokens x 64 experts x 128 d.
// Block = 8 K-subslices; LDS tree-reduce then one atomicAdd per value.
__global__ __launch_bounds__(512, 8) void gemm_mfma(
    const float* __restrict__ xr, const float* __restrict__ xi,
    const unsigned short* __restrict__ F, float* __restrict__ score)
{
    __shared__ float score8[NKW][TSTRIP][EE];   // 32 KB

    const int tid  = threadIdx.x;
    const int wv   = tid >> 6;
    const int lane = tid & 63;
    const int fm   = lane & 15;     // A: token row; D: expert col
    const int fq   = lane >> 4;     // A/B: k-octet; D: row quad
    const int ks   = blockIdx.x & (KSPL - 1);
    const int t0   = (blockIdx.x >> 1) * TSTRIP;
    const int dbase = ks * (DD / KSPL) + wv * DW;

    const float* prx = xr + (size_t)(t0 + fm) * DD + dbase + fq * 8;
    const float* pix = xi + (size_t)(t0 + fm) * DD + dbase + fq * 8;
    // ck for this wave's first chunk: 2*(dbase>>5); ck stride = 4*512 elements
    const unsigned short* bs = F + (size_t)(2 * (dbase >> 5)) * 2048 + lane * 8;

    f32x4 acc[4];
    #pragma unroll
    for (int n = 0; n < 4; ++n) acc[n] = (f32x4){0.f, 0.f, 0.f, 0.f};

    for (int c = 0; c < NCH; ++c) {
        const float4 vr0 = *(const float4*)(prx);
        const float4 vr1 = *(const float4*)(prx + 4);
        const float4 vi0 = *(const float4*)(pix);
        const float4 vi1 = *(const float4*)(pix + 4);
        prx += 32; pix += 32;

        const float ar[8] = {vr0.x, vr0.y, vr0.z, vr0.w, vr1.x, vr1.y, vr1.z, vr1.w};
        const float ai[8] = {vi0.x, vi0.y, vi0.z, vi0.w, vi1.x, vi1.y, vi1.z, vi1.w};

        float av[8], pv[8];
        #pragma unroll
        for (int j = 0; j < 8; ++j) {
            av[j] = __builtin_amdgcn_sqrtf(fmaf(ar[j], ar[j], ai[j] * ai[j]));
            pv[j] = fast_atan2f(ai[j], ar[j]);
        }
        bf16x8 a1, a2, a3, p1, p2, p3;
        split_planes(av, a1, a2, a3);
        split_planes(pv, p1, p2, p3);

        // amp kstep at bs, phase kstep at bs + 2048 (next ck)
        #pragma unroll
        for (int n = 0; n < 4; ++n) {
            const bf16x8 b1 = *(const bf16x8*)(bs + n * 512);
            const bf16x8 b2 = *(const bf16x8*)(bs + n * 512 + F_SSTRIDE);
            const bf16x8 b3 = *(const bf16x8*)(bs + n * 512 + 2 * F_SSTRIDE);
            acc[n] = __builtin_amdgcn_mfma_f32_16x16x32_bf16(a1, b1, acc[n], 0, 0, 0);
            acc[n] = __builtin_amdgcn_mfma_f32_16x16x32_bf16(a1, b2, acc[n], 0, 0, 0);
            acc[n] = __builtin_amdgcn_mfma_f32_16x16x32_bf16(a2, b1, acc[n], 0, 0, 0);
            acc[n] = __builtin_amdgcn_mfma_f32_16x16x32_bf16(a1, b3, acc[n], 0, 0, 0);
            acc[n] = __builtin_amdgcn_mfma_f32_16x16x32_bf16(a2, b2, acc[n], 0, 0, 0);
            acc[n] = __builtin_amdgcn_mfma_f32_16x16x32_bf16(a3, b1, acc[n], 0, 0, 0);
        }
        #pragma unroll
        for (int n = 0; n < 4; ++n) {
            const bf16x8 b1 = *(const bf16x8*)(bs + 2048 + n * 512);
            const bf16x8 b2 = *(const bf16x8*)(bs + 2048 + n * 512 + F_SSTRIDE);
            const bf16x8 b3 = *(const bf16x8*)(bs + 2048 + n * 512 + 2 * F_SSTRIDE);
            acc[n] = __builtin_amdgcn_mfma_f32_16x16x32_bf16(p1, b1, acc[n], 0, 0, 0);
            acc[n] = __builtin_amdgcn_mfma_f32_16x16x32_bf16(p1, b2, acc[n], 0, 0, 0);
            acc[n] = __builtin_amdgcn_mfma_f32_16x16x32_bf16(p2, b1, acc[n], 0, 0, 0);
            acc[n] = __builtin_amdgcn_mfma_f32_16x16x32_bf16(p1, b3, acc[n], 0, 0, 0);
            acc[n] = __builtin_amdgcn_mfma_f32_16x16x32_bf16(p2, b2, acc[n], 0, 0, 0);
            acc[n] = __builtin_amdgcn_mfma_f32_16x16x32_bf16(p3, b1, acc[n], 0, 0, 0);
        }
        bs += 4096;     // 2 cksteps
    }

    // partials to LDS: D layout col=lane&15 (expert), row=(lane>>4)*4+reg (token)
    #pragma unroll
    for (int n = 0; n < 4; ++n)
        #pragma unroll
        for (int r = 0; r < 4; ++r)
            score8[wv][fq * 4 + r][n * 16 + fm] = acc[n][r];
    __syncthreads();

    // reduce 8 sub-slices, one global atomicAdd per (token, expert)
    #pragma unroll
    for (int rep = 0; rep < 2; ++rep) {
        const int p = tid + rep * 512;
        const int tok = p >> 6, e = p & 63;
        float s = score8[0][tok][e];
        #pragma unroll
        for (int w = 1; w < NKW; ++w) s += score8[w][tok][e];
        atomicAdd(&score[(size_t)(t0 + tok) * EE + e], s);
    }
}

// Kernel 2: per token add bias, exact top-2 (tie-break lower index), outputs.
__global__ __launch_bounds__(256) void finalize_topk(
    const float* __restrict__ score, const float* __restrict__ bias,
    float* __restrict__ out)
{
    const int tid  = threadIdx.x;
    const int lane = tid & 63;   // = expert
    const int w    = tid >> 6;
    const int t    = blockIdx.x * 4 + w;

    float v1 = bias[lane] + score[(size_t)t * EE + lane];
    float v2 = -INFINITY;
    int   i1 = lane, i2 = 64;

    #pragma unroll
    for (int off = 1; off < 64; off <<= 1) {
        const float ov1 = __shfl_xor(v1, off, 64);
        const int   oi1 = __shfl_xor(i1, off, 64);
        const float ov2 = __shfl_xor(v2, off, 64);
        const int   oi2 = __shfl_xor(i2, off, 64);
        const bool b1 = (ov1 > v1) || (ov1 == v1 && oi1 < i1);
        const float n1 = b1 ? ov1 : v1;  const int ni1 = b1 ? oi1 : i1;
        const float c1 = b1 ? v1  : ov1; const int ci1 = b1 ? i1  : oi1;
        const float c2 = b1 ? ov2 : v2;  const int ci2 = b1 ? oi2 : i2;
        const bool b2 = (c1 > c2) || (c1 == c2 && ci1 < ci2);
        v1 = n1; i1 = ni1;
        v2 = b2 ? c1 : c2; i2 = b2 ? ci1 : ci2;
    }

    if (lane == 0) {
        const float z  = expf(v2 - v1);
        const float p1 = 1.0f / (1.0f + z);
        const float p2 = z / (1.0f + z);
        out[(size_t)t * 2 + 0] = p1;
        out[(size_t)t * 2 + 1] = p2;
        out[PROB_N + (size_t)t * 2 + 0] = (float)i1;
        out[PROB_N + (size_t)t * 2 + 1] = (float)i2;
    }
}

extern "C" void kernel_launch(void* const* d_in, const int* in_sizes, int n_in,
                              void* d_out, int out_size, void* d_ws, size_t ws_size,
                              hipStream_t stream) {
    const float* xr = (const float*)d_in[0];
    const float* xi = (const float*)d_in[1];
    const float* W  = (const float*)d_in[2];
    const float* b  = (const float*)d_in[3];
    float* out = (float*)d_out;

    float* score = (float*)d_ws;                                   // 2 MB
    unsigned short* F = (unsigned short*)((char*)d_ws + (size_t)NTOK * EE * 4);  // 1.5 MB

    wsplit<<<128, 256, 0, stream>>>(W, F, score);
    gemm_mfma<<<(NTOK / TSTRIP) * KSPL, 512, 0, stream>>>(xr, xi, F, score);
    finalize_topk<<<NTOK / 4, 256, 0, stream>>>(score, b, out);
}

// Round 7
// 177.796 us; speedup vs baseline: 1.1076x; 1.1076x over previous
//
#include <hip/hip_runtime.h>
#include <math.h>

#define NTOK 8192
#define DD   2048
#define EE   64
#define TSTRIP 16            // tokens per block (one MFMA m-tile)
#define NCH 16               // chunks per K-half (64 d each)
#define PROB_N (NTOK*2)
#define AROW 136             // 128 feats + 8 pad (halves); 272B rows, 16B aligned
// F layout: [plane:2][ck:128][nt:4][lane:64][j:8] fp16 = 1 MB
#define F_PSTRIDE (128*4*64*8)

typedef _Float16 f16x8 __attribute__((ext_vector_type(8)));
typedef _Float16 f16x4 __attribute__((ext_vector_type(4)));
typedef float    f32x4 __attribute__((ext_vector_type(4)));

// fast branchless atan2 (Cephes reduction + deg-7 odd minimax), ~3e-7 abs
__device__ __forceinline__ float fast_atan2f(float y, float x) {
    const float ax = __builtin_fabsf(x), ay = __builtin_fabsf(y);
    const float hi = fmaxf(ax, ay), lo = fminf(ax, ay);
    const bool  big = lo > 0.4142135679721832f * hi;       // tan(pi/8)
    const float num = big ? (lo - hi) : lo;
    const float den = big ? (lo + hi) : hi;
    float rc = __builtin_amdgcn_rcpf(den);
    rc = rc * fmaf(-den, rc, 2.0f);                        // 1 NR step
    const float z  = num * rc;
    const float z2 = z * z;
    float p = fmaf(z2, 8.05374449538e-2f, -1.38776856032e-1f);
    p = fmaf(z2, p, 1.99777106478e-1f);
    p = fmaf(z2, p, -3.33329491539e-1f);
    float r = fmaf(z * z2, p, z);
    r = r + (big ? 0.78539816339744830962f : 0.0f);
    r = (ay > ax) ? (1.57079632679489661923f - r) : r;
    r = (x < 0.0f) ? (3.14159265358979323846f - r) : r;
    return copysignf(r, y);
}

// fp16 2-split with scaled low plane: x ~= h1 + h2s*2^-11, err ~2^-24|x|
__device__ __forceinline__ void fsplit2(float x, _Float16& h1, _Float16& h2s) {
    const _Float16 a = (_Float16)x;                 // RNE, 11 bits
    h1 = a;
    h2s = (_Float16)((x - (float)a) * 2048.0f);     // next ~12 bits, normal-scaled
}

// Kernel 0: split W [4096][64] fp32 -> F fragment-order fp16 (2 planes, 1 MB)
__global__ __launch_bounds__(256) void wsplit(const float* __restrict__ W,
                                              _Float16* __restrict__ F) {
    const int g  = blockIdx.x * 256 + threadIdx.x;   // 32768 threads
    const int e  = g & 63;
    const int q  = g >> 6;          // 0..511
    const int d0 = q * 4;
    const int nt = e >> 4;
    const int lane = ((d0 & 31) >> 3) * 16 + (e & 15);
    const int j0 = d0 & 7;          // 0 or 4
    const int cka = 2 * (d0 >> 5);  // amp kstep; phase kstep = cka+1

    f16x4 a1, a2, p1, p2;
    #pragma unroll
    for (int i = 0; i < 4; ++i) {
        _Float16 h, l;
        fsplit2(W[(size_t)(d0 + i) * EE + e], h, l);      a1[i] = h; a2[i] = l;
        fsplit2(W[(size_t)(DD + d0 + i) * EE + e], h, l); p1[i] = h; p2[i] = l;
    }
    *(f16x4*)&F[((size_t)(0 * 128 + cka)     * 4 + nt) * 512 + lane * 8 + j0] = a1;
    *(f16x4*)&F[((size_t)(1 * 128 + cka)     * 4 + nt) * 512 + lane * 8 + j0] = a2;
    *(f16x4*)&F[((size_t)(0 * 128 + cka + 1) * 4 + nt) * 512 + lane * 8 + j0] = p1;
    *(f16x4*)&F[((size_t)(1 * 128 + cka + 1) * 4 + nt) * 512 + lane * 8 + j0] = p2;
}

// Kernel 1: fully fused. Block = 16 tokens, full K. 8 waves = 4 expert-tiles
// x 2 K-halves. Double-buffered LDS A (amp/phase split once per element),
// B straight from L2 (1KB contiguous wave loads), 3 MFMAs per kstep,
// in-block reduce + bias + exact top-2.
__global__ __launch_bounds__(512, 4) void gemm_topk(
    const float* __restrict__ xr, const float* __restrict__ xi,
    const _Float16* __restrict__ F, const float* __restrict__ bias,
    float* __restrict__ out)
{
    __shared__ __align__(16) _Float16 A[2][2][2][TSTRIP][AROW];  // 34 KB
    __shared__ float scoreH[2][TSTRIP][EE];                       // 8 KB

    const int tid = threadIdx.x;
    const int t0  = blockIdx.x * TSTRIP;
    // compute roles
    const int wv = tid >> 6, lane = tid & 63;
    const int nt = wv & 3, kh = wv >> 2;
    const int fm = lane & 15, fq = lane >> 4;
    // staging roles
    const int kh_s  = tid >> 8;
    const int tok_s = (tid >> 4) & 15;
    const int f4    = tid & 15;

    const float bv = bias[lane];

    const float* prx = xr + (size_t)(t0 + tok_s) * DD + kh_s * 1024 + f4 * 4;
    const float* pix = xi + (size_t)(t0 + tok_s) * DD + kh_s * 1024 + f4 * 4;
    const int posa = 64 * (f4 >> 3) + (f4 & 7) * 4;   // amp slot; phase = +32

    auto sprocess = [&](float4 vr, float4 vi, int buf) {
        const float ar[4] = {vr.x, vr.y, vr.z, vr.w};
        const float ai[4] = {vi.x, vi.y, vi.z, vi.w};
        f16x4 a1, a2, p1, p2;
        #pragma unroll
        for (int i = 0; i < 4; ++i) {
            const float amp = __builtin_amdgcn_sqrtf(fmaf(ar[i], ar[i], ai[i] * ai[i]));
            const float ph  = fast_atan2f(ai[i], ar[i]);
            _Float16 h, l;
            fsplit2(amp, h, l); a1[i] = h; a2[i] = l;
            fsplit2(ph,  h, l); p1[i] = h; p2[i] = l;
        }
        *(f16x4*)&A[buf][kh_s][0][tok_s][posa]      = a1;
        *(f16x4*)&A[buf][kh_s][1][tok_s][posa]      = a2;
        *(f16x4*)&A[buf][kh_s][0][tok_s][posa + 32] = p1;
        *(f16x4*)&A[buf][kh_s][1][tok_s][posa + 32] = p2;
    };

    f32x4 accH = (f32x4){0.f, 0.f, 0.f, 0.f};
    f32x4 accL = (f32x4){0.f, 0.f, 0.f, 0.f};

    // prologue: stage chunk 0
    sprocess(*(const float4*)prx, *(const float4*)pix, 0);
    __syncthreads();

    for (int c = 0; c < NCH; ++c) {
        const int buf = c & 1;
        // issue next chunk's x first (longest latency, covered by B+MFMA below)
        float4 nvr, nvi;
        if (c + 1 < NCH) {
            nvr = *(const float4*)(prx + (c + 1) * 64);
            nvi = *(const float4*)(pix + (c + 1) * 64);
        }
        // B fragments: 4 cksteps x 2 planes, contiguous 1KB wave loads
        const int ck0 = kh * 64 + c * 4;
        const _Float16* b1p = F + ((size_t)ck0 * 4 + nt) * 512 + lane * 8;
        const _Float16* b2p = b1p + F_PSTRIDE;
        f16x8 b1[4], b2[4], a1[4], a2[4];
        #pragma unroll
        for (int j = 0; j < 4; ++j) {
            b1[j] = *(const f16x8*)(b1p + j * 2048);
            b2[j] = *(const f16x8*)(b2p + j * 2048);
        }
        #pragma unroll
        for (int j = 0; j < 4; ++j) {
            a1[j] = *(const f16x8*)&A[buf][kh][0][fm][j * 32 + fq * 8];
            a2[j] = *(const f16x8*)&A[buf][kh][1][fm][j * 32 + fq * 8];
        }
        #pragma unroll
        for (int j = 0; j < 4; ++j) {
            accH = __builtin_amdgcn_mfma_f32_16x16x32_f16(a1[j], b1[j], accH, 0, 0, 0);
            accL = __builtin_amdgcn_mfma_f32_16x16x32_f16(a1[j], b2[j], accL, 0, 0, 0);
            accL = __builtin_amdgcn_mfma_f32_16x16x32_f16(a2[j], b1[j], accL, 0, 0, 0);
        }
        if (c + 1 < NCH) sprocess(nvr, nvi, buf ^ 1);
        __syncthreads();
    }

    // D layout: col(expert-in-tile)=lane&15, row(token)=(lane>>4)*4+reg [m89]
    #pragma unroll
    for (int r = 0; r < 4; ++r)
        scoreH[kh][fq * 4 + r][nt * 16 + fm] = fmaf(accL[r], 4.8828125e-4f, accH[r]);
    __syncthreads();

    // exact top-2 (tie-break lower index, matching lax.top_k); 2 tokens/wave
    #pragma unroll
    for (int rep = 0; rep < 2; ++rep) {
        const int tok = wv * 2 + rep;
        float v1 = scoreH[0][tok][lane] + scoreH[1][tok][lane] + bv;
        float v2 = -INFINITY;
        int   i1 = lane, i2 = 64;
        #pragma unroll
        for (int off = 1; off < 64; off <<= 1) {
            const float ov1 = __shfl_xor(v1, off, 64);
            const int   oi1 = __shfl_xor(i1, off, 64);
            const float ov2 = __shfl_xor(v2, off, 64);
            const int   oi2 = __shfl_xor(i2, off, 64);
            const bool b1 = (ov1 > v1) || (ov1 == v1 && oi1 < i1);
            const float n1 = b1 ? ov1 : v1;  const int ni1 = b1 ? oi1 : i1;
            const float c1 = b1 ? v1  : ov1; const int ci1 = b1 ? i1  : oi1;
            const float c2 = b1 ? ov2 : v2;  const int ci2 = b1 ? oi2 : i2;
            const bool b2 = (c1 > c2) || (c1 == c2 && ci1 < ci2);
            v1 = n1; i1 = ni1;
            v2 = b2 ? c1 : c2; i2 = b2 ? ci1 : ci2;
        }
        if (lane == 0) {
            const int t = t0 + tok;
            const float z  = expf(v2 - v1);
            const float p1 = 1.0f / (1.0f + z);
            const float p2 = z / (1.0f + z);
            out[(size_t)t * 2 + 0] = p1;
            out[(size_t)t * 2 + 1] = p2;
            out[PROB_N + (size_t)t * 2 + 0] = (float)i1;
            out[PROB_N + (size_t)t * 2 + 1] = (float)i2;
        }
    }
}

extern "C" void kernel_launch(void* const* d_in, const int* in_sizes, int n_in,
                              void* d_out, int out_size, void* d_ws, size_t ws_size,
                              hipStream_t stream) {
    const float* xr = (const float*)d_in[0];
    const float* xi = (const float*)d_in[1];
    const float* W  = (const float*)d_in[2];
    const float* b  = (const float*)d_in[3];
    float* out = (float*)d_out;
    _Float16* F = (_Float16*)d_ws;   // 1 MB swizzled 2-plane fp16 W

    wsplit<<<128, 256, 0, stream>>>(W, F);
    gemm_topk<<<NTOK / TSTRIP, 512, 0, stream>>>(xr, xi, F, b, out);
}